// Round 4
// baseline (139.932 us; speedup 1.0000x reference)
//
#include <hip/hip_runtime.h>
#include <hip/hip_bf16.h>

// CategorySpecificLinear: out[b,t,h] = sum_d x[b,t,d] * W[cat[b],d,h] + bias[cat[b],h]
// B=256, T=32, D=1024, H=1024, NCAT=32.
// R4: fix XCD load imbalance (spread active records uniformly over the table so
// each XCD chunk gets ~equal active blocks), BN=64 for 2x more blocks (TLP to
// hide L3 latency), keep 3-deep register pipeline + double-buffered LDS + raw
// s_barrier with lgkmcnt-only drain.

#define NCAT 32
#define DIN  1024
#define DH   1024
#define NBATCH 256
#define TT   32
#define MAXREC 96

#define BM 128
#define BN 64
#define BK 32
#define LDK 40   // LDS row stride in bf16 elems (BK + 8 pad)
#define NITER (DIN / BK)   // 32
#define NTILES (DH / BN)   // 16
#define NWG (MAXREC * NTILES)          // 1536
#define CHUNK (NWG / 8)                // 192 per XCD

typedef __attribute__((ext_vector_type(4))) float f32x4;
typedef __attribute__((ext_vector_type(8))) short bf16x8;
typedef __attribute__((ext_vector_type(4))) short bf16x4;

__device__ inline short f2bf(float f) {
    unsigned u = __builtin_bit_cast(unsigned, f);
    u += 0x7fffu + ((u >> 16) & 1u);
    return (short)(u >> 16);
}

// ---------------------------------------------------------------------------
// Setup: bucket batches by category into compact records {cat,nb,b0..b3,pad2},
// then SPREAD the nact active records uniformly over MAXREC slots so the
// XCD-chunked swizzle gives every XCD ~nact/8 active records.
// ---------------------------------------------------------------------------
__global__ void cat_setup_kernel(const int* __restrict__ cat_ids,
                                 int* __restrict__ recs) {
    __shared__ int cats[NBATCH];
    __shared__ int offs[NCAT + 1];
    __shared__ int cbuf[MAXREC * 8];
    const int t = threadIdx.x;
    cats[t] = cat_ids[t];
    for (int i = t; i < MAXREC * 8; i += 256) { cbuf[i] = 0; recs[i] = 0; }
    __syncthreads();
    if (t < NCAT) {
        int cnt = 0;
        for (int i = 0; i < NBATCH; ++i) cnt += (cats[i] == t) ? 1 : 0;
        offs[t + 1] = (cnt + 3) >> 2;
    }
    __syncthreads();
    if (t == 0) {
        offs[0] = 0;
        for (int c = 0; c < NCAT; ++c) offs[c + 1] += offs[c];
    }
    __syncthreads();
    if (t < NCAT) {
        int base = offs[t];
        int b0 = 0, b1 = 0, b2 = 0, b3 = 0;
        int nb = 0, k = 0;
        for (int i = 0; i < NBATCH; ++i) {
            if (cats[i] == t) {
                if (nb == 0) b0 = i; else if (nb == 1) b1 = i;
                else if (nb == 2) b2 = i; else b3 = i;
                ++nb;
                if (nb == 4) {
                    int* r = cbuf + (base + k) * 8;
                    r[0] = t; r[1] = 4; r[2] = b0; r[3] = b1; r[4] = b2; r[5] = b3;
                    ++k; nb = 0;
                }
            }
        }
        if (nb > 0) {
            int* r = cbuf + (base + k) * 8;
            r[0] = t; r[1] = nb;
            r[2] = b0;
            r[3] = (nb > 1) ? b1 : b0;
            r[4] = (nb > 2) ? b2 : b0;
            r[5] = (nb > 3) ? b3 : b0;
        }
    }
    __syncthreads();
    const int nact = offs[NCAT];   // <= 88
    // scatter record r -> slot r*MAXREC/nact (strictly increasing, injective)
    for (int i = t; i < MAXREC * 8; i += 256) {
        const int r = i >> 3, f = i & 7;
        if (r < nact) recs[(r * MAXREC / nact) * 8 + f] = cbuf[i];
    }
}

// One K-step: convert+stage tile `it`, prefetch tile it+2 into the just-freed
// register set, barrier (lgkm-only drain), ds_read fragments, 8 MFMAs.
__device__ __forceinline__ void gemm_step(
    f32x4 (&xv)[4], f32x4 (&wv)[2],
    short* xd, short* wdb,
    const short* ap, const short* bp,
    const float* xsrc, const float* wsrc,
    int wn4, int wk2, int it,
    f32x4 (&acc)[4][2]) {

    // --- X: convert 16 fp32 -> bf16, two 16B LDS writes ---
    bf16x8 p0, p1;
#pragma unroll
    for (int i = 0; i < 4; ++i) {
        p0[i]     = f2bf(xv[0][i]);
        p0[i + 4] = f2bf(xv[1][i]);
        p1[i]     = f2bf(xv[2][i]);
        p1[i + 4] = f2bf(xv[3][i]);
    }
    *(bf16x8*)(xd)     = p0;
    *(bf16x8*)(xd + 8) = p1;

    // --- W: 2x4 register transpose -> four b32 writes wt[n][k..k+1] ---
#pragma unroll
    for (int j = 0; j < 4; ++j) {
        unsigned pk = (unsigned)(unsigned short)f2bf(wv[0][j]) |
                      ((unsigned)(unsigned short)f2bf(wv[1][j]) << 16);
        *(unsigned*)(wdb + (wn4 + j) * LDK + wk2) = pk;
    }

    // --- prefetch tile it+2 into the just-freed register set ---
    if (it + 2 < NITER) {
        const int k0 = (it + 2) * BK;
#pragma unroll
        for (int i = 0; i < 4; ++i)
            xv[i] = *(const f32x4*)(xsrc + k0 + i * 4);
        wv[0] = *(const f32x4*)(wsrc + (size_t)k0 * DH);
        wv[1] = *(const f32x4*)(wsrc + (size_t)(k0 + 1) * DH);
    }

    // drain LDS writes only — prefetch loads stay in flight across the barrier
    asm volatile("s_waitcnt lgkmcnt(0)" ::: "memory");
    __builtin_amdgcn_s_barrier();
    asm volatile("" ::: "memory");

    // --- fragments + MFMA on tile `it` ---
    bf16x8 af[4], bfr[2];
#pragma unroll
    for (int mi = 0; mi < 4; ++mi)
        af[mi] = *(const bf16x8*)(ap + mi * 16 * LDK);
#pragma unroll
    for (int ni = 0; ni < 2; ++ni)
        bfr[ni] = *(const bf16x8*)(bp + ni * 16 * LDK);

#pragma unroll
    for (int mi = 0; mi < 4; ++mi)
#pragma unroll
        for (int ni = 0; ni < 2; ++ni)
            acc[mi][ni] = __builtin_amdgcn_mfma_f32_16x16x32_bf16(
                af[mi], bfr[ni], acc[mi][ni], 0, 0, 0);
    // next step writes the other LDS buffer; buffer reuse two steps ahead is
    // ordered by the next barrier's preceding lgkmcnt(0).
}

// ---------------------------------------------------------------------------
// Grouped GEMM. 256 threads = 4 waves (2x2), wave tile 64x32.
// ---------------------------------------------------------------------------
__launch_bounds__(256, 3)
__global__ void cat_gemm_kernel(const float* __restrict__ x,
                                const float* __restrict__ W,
                                const float* __restrict__ bias,
                                const int* __restrict__ recs,
                                float* __restrict__ out) {
    // XCD-chunked swizzle: 1536 blocks = 8 XCDs x 192 consecutive lins.
    const int wg    = blockIdx.x;
    const int lin   = (wg & 7) * CHUNK + (wg >> 3);
    const int irec  = lin >> 4;      // /NTILES
    const int ntile = lin & 15;

    const int* rec = recs + irec * 8;
    const int cat = rec[0];
    const int nb  = rec[1];
    if (nb == 0) return;
    const int n0 = ntile * BN;

    __shared__ short xs[2][BM * LDK];   // 20.0 KB
    __shared__ short wt[2][BN * LDK];   // 10.0 KB

    const int t    = threadIdx.x;
    const int lane = t & 63;
    const int wid  = t >> 6;
    const int wm   = wid >> 1;
    const int wn   = wid & 1;
    const int fl   = lane & 15;
    const int kb   = lane >> 4;

    // X staging: row xr = t>>1, 16 cols at xc0
    const int xr     = t >> 1;
    const int xc0    = (t & 1) * 16;
    const int xbatch = rec[2 + (xr >> 5)];
    const float* xsrc = x + (size_t)(xbatch * TT + (xr & 31)) * DIN + xc0;
    short* xdst0 = &xs[0][0] + xr * LDK + xc0;
    short* xdst1 = &xs[1][0] + xr * LDK + xc0;

    // W staging: k rows wk2, wk2+1; n cols wn4..wn4+3 (2x4 register transpose)
    const int wk2 = (t & 15) * 2;        // 0..30
    const int wn4 = (t >> 4) * 4;        // 0..60
    const float* wsrc = W + (size_t)cat * (DIN * DH) + (size_t)wk2 * DH + n0 + wn4;

    // bias early (latency hidden under K loop)
    float bv[2];
#pragma unroll
    for (int ni = 0; ni < 2; ++ni)
        bv[ni] = bias[cat * DH + n0 + wn * 32 + ni * 16 + fl];

    f32x4 acc[4][2];
#pragma unroll
    for (int i = 0; i < 4; ++i)
#pragma unroll
        for (int j = 0; j < 2; ++j)
            acc[i][j] = (f32x4){0.f, 0.f, 0.f, 0.f};

    const short* ap0 = &xs[0][0] + (wm * 64 + fl) * LDK + kb * 8;
    const short* ap1 = &xs[1][0] + (wm * 64 + fl) * LDK + kb * 8;
    const short* bp0 = &wt[0][0] + (wn * 32 + fl) * LDK + kb * 8;
    const short* bp1 = &wt[1][0] + (wn * 32 + fl) * LDK + kb * 8;

    // prologue: load K-tiles 0 (set A) and 1 (set B)
    f32x4 xvA[4], xvB[4];
    f32x4 wvA[2], wvB[2];
#pragma unroll
    for (int i = 0; i < 4; ++i) xvA[i] = *(const f32x4*)(xsrc + i * 4);
    wvA[0] = *(const f32x4*)(wsrc);
    wvA[1] = *(const f32x4*)(wsrc + DH);
#pragma unroll
    for (int i = 0; i < 4; ++i) xvB[i] = *(const f32x4*)(xsrc + BK + i * 4);
    wvB[0] = *(const f32x4*)(wsrc + (size_t)BK * DH);
    wvB[1] = *(const f32x4*)(wsrc + (size_t)(BK + 1) * DH);

    for (int it = 0; it < NITER; it += 2) {
        gemm_step(xvA, wvA, xdst0, &wt[0][0], ap0, bp0, xsrc, wsrc, wn4, wk2, it,     acc);
        gemm_step(xvB, wvB, xdst1, &wt[1][0], ap1, bp1, xsrc, wsrc, wn4, wk2, it + 1, acc);
    }

    // --- epilogue: bias + store rows of real batches ---
#pragma unroll
    for (int mi = 0; mi < 4; ++mi) {
        const int slot = wm * 2 + (mi >> 1);
        if (slot < nb) {
            const int batch = rec[2 + slot];
            const int rbase = wm * 64 + mi * 16 + kb * 4;
#pragma unroll
            for (int j = 0; j < 4; ++j) {
                const int trow = (rbase + j) & 31;
                float* orow = out + (size_t)(batch * TT + trow) * DH + n0 + wn * 32;
#pragma unroll
                for (int ni = 0; ni < 2; ++ni)
                    orow[ni * 16 + fl] = acc[mi][ni][j] + bv[ni];
            }
        }
    }
}

extern "C" void kernel_launch(void* const* d_in, const int* in_sizes, int n_in,
                              void* d_out, int out_size, void* d_ws, size_t ws_size,
                              hipStream_t stream) {
    const float* x       = (const float*)d_in[0];
    const int*   cat_ids = (const int*)d_in[1];
    const float* W       = (const float*)d_in[2];
    const float* bias    = (const float*)d_in[3];
    float*       out     = (float*)d_out;
    int*         recs    = (int*)d_ws;

    hipLaunchKernelGGL(cat_setup_kernel, dim3(1), dim3(256), 0, stream,
                       cat_ids, recs);
    hipLaunchKernelGGL(cat_gemm_kernel, dim3(NWG), dim3(256), 0, stream,
                       x, W, bias, recs, out);
}

// Round 6
// 125.948 us; speedup vs baseline: 1.1110x; 1.1110x over previous
//
#include <hip/hip_runtime.h>
#include <hip/hip_bf16.h>

// CategorySpecificLinear: out[b,t,h] = sum_d x[b,t,d] * W[cat[b],d,h] + bias[cat[b],h]
// R6: R5 with the X-staging row-index bug fixed (xrow, not xrow*4).
// Fully-coalesced X staging (each wave instr = 8 rows x 128B fully consumed),
// BN=128 / 768 blocks, record-spreading for XCD balance, 3-deep register
// pipeline + double-buffered LDS + raw s_barrier with lgkmcnt-only drain.

#define NCAT 32
#define DIN  1024
#define DH   1024
#define NBATCH 256
#define TT   32
#define MAXREC 96

#define BM 128
#define BN 128
#define BK 32
#define LDK 40   // LDS row stride in bf16 elems (BK + 8 pad)
#define NITER (DIN / BK)   // 32
#define NTILES (DH / BN)   // 8
#define NWG (MAXREC * NTILES)          // 768
#define CHUNK (NWG / 8)                // 96 per XCD

typedef __attribute__((ext_vector_type(4))) float f32x4;
typedef __attribute__((ext_vector_type(8))) short bf16x8;
typedef __attribute__((ext_vector_type(4))) short bf16x4;

__device__ inline short f2bf(float f) {
    unsigned u = __builtin_bit_cast(unsigned, f);
    u += 0x7fffu + ((u >> 16) & 1u);
    return (short)(u >> 16);
}

// ---------------------------------------------------------------------------
// Setup: bucket batches by category into compact records {cat,nb,b0..b3,pad2},
// then spread the nact active records uniformly over MAXREC slots (XCD balance).
// ---------------------------------------------------------------------------
__global__ void cat_setup_kernel(const int* __restrict__ cat_ids,
                                 int* __restrict__ recs) {
    __shared__ int cats[NBATCH];
    __shared__ int offs[NCAT + 1];
    __shared__ int cbuf[MAXREC * 8];
    const int t = threadIdx.x;
    cats[t] = cat_ids[t];
    for (int i = t; i < MAXREC * 8; i += 256) { cbuf[i] = 0; recs[i] = 0; }
    __syncthreads();
    if (t < NCAT) {
        int cnt = 0;
        for (int i = 0; i < NBATCH; ++i) cnt += (cats[i] == t) ? 1 : 0;
        offs[t + 1] = (cnt + 3) >> 2;
    }
    __syncthreads();
    if (t == 0) {
        offs[0] = 0;
        for (int c = 0; c < NCAT; ++c) offs[c + 1] += offs[c];
    }
    __syncthreads();
    if (t < NCAT) {
        int base = offs[t];
        int b0 = 0, b1 = 0, b2 = 0, b3 = 0;
        int nb = 0, k = 0;
        for (int i = 0; i < NBATCH; ++i) {
            if (cats[i] == t) {
                if (nb == 0) b0 = i; else if (nb == 1) b1 = i;
                else if (nb == 2) b2 = i; else b3 = i;
                ++nb;
                if (nb == 4) {
                    int* r = cbuf + (base + k) * 8;
                    r[0] = t; r[1] = 4; r[2] = b0; r[3] = b1; r[4] = b2; r[5] = b3;
                    ++k; nb = 0;
                }
            }
        }
        if (nb > 0) {
            int* r = cbuf + (base + k) * 8;
            r[0] = t; r[1] = nb;
            r[2] = b0;
            r[3] = (nb > 1) ? b1 : b0;
            r[4] = (nb > 2) ? b2 : b0;
            r[5] = (nb > 3) ? b3 : b0;
        }
    }
    __syncthreads();
    const int nact = offs[NCAT];   // <= 88
    for (int i = t; i < MAXREC * 8; i += 256) {
        const int r = i >> 3, f = i & 7;
        if (r < nact) recs[(r * MAXREC / nact) * 8 + f] = cbuf[i];
    }
}

// One K-step. xv[i] = X row (wid*32 + i*8 + (l>>3)), k-elems (l&7)*4..+3.
// wv[i] = W row wk4+i, n-elems wn4..+3.
__device__ __forceinline__ void gemm_step(
    f32x4 (&xv)[4], f32x4 (&wv)[4],
    short* xd, short* wdb,
    const short* ap, const short* bp,
    const float* xsrc, const float* wsrc,
    int wn4, int wk4, int it,
    f32x4 (&acc)[4][4]) {

    // --- X: convert, 4x b64 LDS writes (rows i*8 apart) ---
#pragma unroll
    for (int i = 0; i < 4; ++i) {
        bf16x4 q;
        q[0] = f2bf(xv[i][0]);
        q[1] = f2bf(xv[i][1]);
        q[2] = f2bf(xv[i][2]);
        q[3] = f2bf(xv[i][3]);
        *(bf16x4*)(xd + i * 8 * LDK) = q;
    }

    // --- W: 4x4 register transpose -> 4x b64 writes wt[n][k] ---
#pragma unroll
    for (int j = 0; j < 4; ++j) {
        bf16x4 q;
        q[0] = f2bf(wv[0][j]);
        q[1] = f2bf(wv[1][j]);
        q[2] = f2bf(wv[2][j]);
        q[3] = f2bf(wv[3][j]);
        *(bf16x4*)(wdb + (wn4 + j) * LDK + wk4) = q;
    }

    // --- prefetch tile it+2 into the just-freed register set ---
    if (it + 2 < NITER) {
        const int k0 = (it + 2) * BK;
#pragma unroll
        for (int i = 0; i < 4; ++i)
            xv[i] = *(const f32x4*)(xsrc + k0 + (size_t)(i * 8) * DIN);
#pragma unroll
        for (int i = 0; i < 4; ++i)
            wv[i] = *(const f32x4*)(wsrc + (size_t)(k0 + i) * DH);
    }

    // drain LDS writes only — prefetch loads stay in flight across the barrier
    asm volatile("s_waitcnt lgkmcnt(0)" ::: "memory");
    __builtin_amdgcn_s_barrier();
    asm volatile("" ::: "memory");

    // --- fragments + MFMA on tile `it` ---
    bf16x8 af[4], bfr[4];
#pragma unroll
    for (int mi = 0; mi < 4; ++mi)
        af[mi] = *(const bf16x8*)(ap + mi * 16 * LDK);
#pragma unroll
    for (int ni = 0; ni < 4; ++ni)
        bfr[ni] = *(const bf16x8*)(bp + ni * 16 * LDK);

#pragma unroll
    for (int mi = 0; mi < 4; ++mi)
#pragma unroll
        for (int ni = 0; ni < 4; ++ni)
            acc[mi][ni] = __builtin_amdgcn_mfma_f32_16x16x32_bf16(
                af[mi], bfr[ni], acc[mi][ni], 0, 0, 0);
    // next step writes the other LDS buffer; buffer reuse two steps ahead is
    // ordered by the next barrier's preceding lgkmcnt(0).
}

// ---------------------------------------------------------------------------
// Grouped GEMM. 256 threads = 4 waves (2x2), wave tile 64x64.
// ---------------------------------------------------------------------------
__launch_bounds__(256, 2)
__global__ void cat_gemm_kernel(const float* __restrict__ x,
                                const float* __restrict__ W,
                                const float* __restrict__ bias,
                                const int* __restrict__ recs,
                                float* __restrict__ out) {
    const int wg    = blockIdx.x;
    const int lin   = (wg & 7) * CHUNK + (wg >> 3);
    const int irec  = lin >> 3;
    const int ntile = lin & 7;

    const int* rec = recs + irec * 8;
    const int cat = rec[0];
    const int nb  = rec[1];
    if (nb == 0) return;
    const int n0 = ntile * BN;

    __shared__ short xs[2][BM * LDK];
    __shared__ short wt[2][BN * LDK];

    const int t    = threadIdx.x;
    const int lane = t & 63;
    const int wid  = t >> 6;
    const int wm   = wid >> 1;
    const int wn   = wid & 1;
    const int fl   = lane & 15;
    const int kb   = lane >> 4;

    // X staging (coalesced): lane -> batch row i*8 + (lane>>3), k (lane&7)*4;
    // LDS row wid*32 + i*8 + (lane>>3). Batch is wave-uniform: rec[2+wid].
    const int xrow   = (lane >> 3);          // 0..7
    const int xk4    = (lane & 7) * 4;       // 0..28
    const int xbatch = rec[2 + wid];         // wave-uniform
    const float* xsrc = x + (size_t)(xbatch * TT + xrow) * DIN + xk4;
    short* xdst0 = &xs[0][0] + (wid * 32 + xrow) * LDK + xk4;
    short* xdst1 = &xs[1][0] + (wid * 32 + xrow) * LDK + xk4;

    // W staging (coalesced): rows wk4+i, n cols wn4..+3 (4x4 register transpose)
    const int wk4 = (t & 7) * 4;
    const int wn4 = (t >> 3) * 4;
    const float* wsrc = W + (size_t)cat * (DIN * DH) + (size_t)wk4 * DH + n0 + wn4;

    float bv[4];
#pragma unroll
    for (int ni = 0; ni < 4; ++ni)
        bv[ni] = bias[cat * DH + n0 + wn * 64 + ni * 16 + fl];

    f32x4 acc[4][4];
#pragma unroll
    for (int i = 0; i < 4; ++i)
#pragma unroll
        for (int j = 0; j < 4; ++j)
            acc[i][j] = (f32x4){0.f, 0.f, 0.f, 0.f};

    const short* ap0 = &xs[0][0] + (wm * 64 + fl) * LDK + kb * 8;
    const short* ap1 = &xs[1][0] + (wm * 64 + fl) * LDK + kb * 8;
    const short* bp0 = &wt[0][0] + (wn * 64 + fl) * LDK + kb * 8;
    const short* bp1 = &wt[1][0] + (wn * 64 + fl) * LDK + kb * 8;

    // prologue: load K-tiles 0 (set A) and 1 (set B)
    f32x4 xvA[4], wvA[4], xvB[4], wvB[4];
#pragma unroll
    for (int i = 0; i < 4; ++i) xvA[i] = *(const f32x4*)(xsrc + (size_t)(i * 8) * DIN);
#pragma unroll
    for (int i = 0; i < 4; ++i) wvA[i] = *(const f32x4*)(wsrc + (size_t)i * DH);
#pragma unroll
    for (int i = 0; i < 4; ++i) xvB[i] = *(const f32x4*)(xsrc + BK + (size_t)(i * 8) * DIN);
#pragma unroll
    for (int i = 0; i < 4; ++i) wvB[i] = *(const f32x4*)(wsrc + (size_t)(BK + i) * DH);

    for (int it = 0; it < NITER; it += 2) {
        gemm_step(xvA, wvA, xdst0, &wt[0][0], ap0, bp0, xsrc, wsrc, wn4, wk4, it,     acc);
        gemm_step(xvB, wvB, xdst1, &wt[1][0], ap1, bp1, xsrc, wsrc, wn4, wk4, it + 1, acc);
    }

    // --- epilogue: bias + store rows of real batches ---
#pragma unroll
    for (int mi = 0; mi < 4; ++mi) {
        const int slot = wm * 2 + (mi >> 1);
        if (slot < nb) {
            const int batch = rec[2 + slot];
            const int rbase = wm * 64 + mi * 16 + kb * 4;
#pragma unroll
            for (int j = 0; j < 4; ++j) {
                const int trow = (rbase + j) & 31;
                float* orow = out + (size_t)(batch * TT + trow) * DH + n0 + wn * 64;
#pragma unroll
                for (int ni = 0; ni < 4; ++ni)
                    orow[ni * 16 + fl] = acc[mi][ni][j] + bv[ni];
            }
        }
    }
}

extern "C" void kernel_launch(void* const* d_in, const int* in_sizes, int n_in,
                              void* d_out, int out_size, void* d_ws, size_t ws_size,
                              hipStream_t stream) {
    const float* x       = (const float*)d_in[0];
    const int*   cat_ids = (const int*)d_in[1];
    const float* W       = (const float*)d_in[2];
    const float* bias    = (const float*)d_in[3];
    float*       out     = (float*)d_out;
    int*         recs    = (int*)d_ws;

    hipLaunchKernelGGL(cat_setup_kernel, dim3(1), dim3(256), 0, stream,
                       cat_ids, recs);
    hipLaunchKernelGGL(cat_gemm_kernel, dim3(NWG), dim3(256), 0, stream,
                       x, W, bias, recs, out);
}

// Round 7
// 82.380 us; speedup vs baseline: 1.6986x; 1.5289x over previous
//
#include <hip/hip_runtime.h>
#include <hip/hip_bf16.h>

// CategorySpecificLinear: out[b,t,h] = sum_d x[b,t,d] * W[cat[b],d,h] + bias[cat[b],h]
// R7: one record per category (<=16 batches, BM=512), BN=64, 1024-thread
// 16-wave blocks. W read ~once from L3 (132 MB vs 287). Record's 16 ntiles on
// one XCD (X L2-shared). Desc-count sort + round-robin XCD deal for balance.
// Per-wave predicates skip staging/MFMA for empty batch slots. Distance-1
// register prefetch + double-buffered LDS + raw s_barrier (lgkm-only drain).

#define NCAT 32
#define DIN  1024
#define DH   1024
#define NBATCH 256
#define TT   32
#define NRECPAD 48     // record slots (multiple of 8); sum ceil(cnt/16) <= 48
#define RSTRIDE 20     // ints per record: cat, nb, b0..b15, pad2

#define BM 512
#define BN 64
#define BK 32
#define LDK 40         // LDS row stride in bf16 elems (BK + 8 pad)
#define NITER (DIN / BK)   // 32
#define NTILES (DH / BN)   // 16

typedef __attribute__((ext_vector_type(4))) float f32x4;
typedef __attribute__((ext_vector_type(8))) short bf16x8;
typedef __attribute__((ext_vector_type(4))) short bf16x4;

__device__ inline short f2bf(float f) {
    unsigned u = __builtin_bit_cast(unsigned, f);
    u += 0x7fffu + ((u >> 16) & 1u);
    return (short)(u >> 16);
}

// ---------------------------------------------------------------------------
// Setup: group batches by category into records of <=16 batches, sort records
// by count desc (stable), write to recs[rank]. Rank r runs on XCD r%8.
// ---------------------------------------------------------------------------
__global__ void cat_setup_kernel(const int* __restrict__ cat_ids,
                                 int* __restrict__ recs) {
    __shared__ int cats[NBATCH];
    __shared__ int cnt[NCAT];
    __shared__ int off[NCAT + 1];
    __shared__ int rstart[NCAT + 1];
    __shared__ int blist[NBATCH];
    __shared__ int cbuf[NRECPAD * RSTRIDE];
    __shared__ int nrec_s;
    const int t = threadIdx.x;
    cats[t] = cat_ids[t];
    for (int i = t; i < NRECPAD * RSTRIDE; i += 256) cbuf[i] = 0;
    __syncthreads();
    if (t < NCAT) {
        int c = 0;
        for (int i = 0; i < NBATCH; ++i) c += (cats[i] == t) ? 1 : 0;
        cnt[t] = c;
    }
    __syncthreads();
    if (t == 0) {
        off[0] = 0; rstart[0] = 0;
        for (int c = 0; c < NCAT; ++c) {
            off[c + 1] = off[c] + cnt[c];
            rstart[c + 1] = rstart[c] + (cnt[c] + 15) / 16;
        }
        nrec_s = rstart[NCAT];
    }
    __syncthreads();
    {   // stable scatter: batches grouped by cat
        int c = cats[t], rank = 0;
        for (int i = 0; i < t; ++i) rank += (cats[i] == c) ? 1 : 0;
        blist[off[c] + rank] = t;
    }
    __syncthreads();
    if (t < NCAT) {   // build this cat's records
        int base = off[t], rem = cnt[t], k = 0;
        while (rem > 0) {
            int nb = rem < 16 ? rem : 16;
            int* rb = cbuf + (rstart[t] + k) * RSTRIDE;
            rb[0] = t; rb[1] = nb;
            for (int i = 0; i < nb; ++i) rb[2 + i] = blist[base + i];
            for (int i = nb; i < 16; ++i) rb[2 + i] = rb[2];
            base += nb; rem -= nb; ++k;
        }
    }
    __syncthreads();
    for (int i = t; i < NRECPAD * RSTRIDE; i += 256) recs[i] = 0;
    __syncthreads();
    const int nrec = nrec_s;
    if (t < nrec) {   // rank by nb desc (stable), write
        const int mynb = cbuf[t * RSTRIDE + 1];
        int rank = 0;
        for (int i = 0; i < nrec; ++i) {
            const int nbi = cbuf[i * RSTRIDE + 1];
            rank += ((nbi > mynb) || (nbi == mynb && i < t)) ? 1 : 0;
        }
        for (int f = 0; f < RSTRIDE; ++f)
            recs[rank * RSTRIDE + f] = cbuf[t * RSTRIDE + f];
    }
}

// One K-step: convert+stage tile it (predicated), prefetch tile it+1 into the
// same regs, barrier (lgkm-only drain), fragments + 8 MFMA (predicated).
__device__ __forceinline__ void gemm_step(
    f32x4 (&xv)[4], f32x4 (&wv)[4],
    short* xd, short* wd,
    const short* ap, const short* bp,
    const float* xsrc, const float* wsrc,
    bool xact, bool wact, bool mact,
    int wn4, int wk4, int it,
    f32x4 (&acc)[4][2]) {

    if (xact) {
#pragma unroll
        for (int i = 0; i < 4; ++i) {
            bf16x4 q;
            q[0] = f2bf(xv[i][0]);
            q[1] = f2bf(xv[i][1]);
            q[2] = f2bf(xv[i][2]);
            q[3] = f2bf(xv[i][3]);
            *(bf16x4*)(xd + i * 8 * LDK) = q;
        }
    }
    if (wact) {
#pragma unroll
        for (int j = 0; j < 4; ++j) {
            bf16x4 q;
            q[0] = f2bf(wv[0][j]);
            q[1] = f2bf(wv[1][j]);
            q[2] = f2bf(wv[2][j]);
            q[3] = f2bf(wv[3][j]);
            *(bf16x4*)(wd + (wn4 + j) * LDK + wk4) = q;
        }
    }

    if (it + 1 < NITER) {
        const int k0 = (it + 1) * BK;
        if (xact) {
#pragma unroll
            for (int i = 0; i < 4; ++i)
                xv[i] = *(const f32x4*)(xsrc + k0 + (size_t)(i * 8) * DIN);
        }
        if (wact) {
#pragma unroll
            for (int i = 0; i < 4; ++i)
                wv[i] = *(const f32x4*)(wsrc + (size_t)(k0 + i) * DH);
        }
    }

    asm volatile("s_waitcnt lgkmcnt(0)" ::: "memory");
    __builtin_amdgcn_s_barrier();
    asm volatile("" ::: "memory");

    if (mact) {
        bf16x8 af[4], bfr[2];
#pragma unroll
        for (int mi = 0; mi < 4; ++mi)
            af[mi] = *(const bf16x8*)(ap + mi * 16 * LDK);
#pragma unroll
        for (int ni = 0; ni < 2; ++ni)
            bfr[ni] = *(const bf16x8*)(bp + ni * 16 * LDK);
#pragma unroll
        for (int mi = 0; mi < 4; ++mi)
#pragma unroll
            for (int ni = 0; ni < 2; ++ni)
                acc[mi][ni] = __builtin_amdgcn_mfma_f32_16x16x32_bf16(
                    af[mi], bfr[ni], acc[mi][ni], 0, 0, 0);
    }
}

// ---------------------------------------------------------------------------
// Grouped GEMM. 1024 threads = 16 waves (8m x 2n), wave tile 64x32.
// wg -> (record rank r, ntile j) with all 16 ntiles of r on XCD r%8.
// ---------------------------------------------------------------------------
__global__ __launch_bounds__(1024)
void cat_gemm_kernel(const float* __restrict__ x,
                     const float* __restrict__ W,
                     const float* __restrict__ bias,
                     const int* __restrict__ recs,
                     float* __restrict__ out) {
    const int wg  = blockIdx.x;
    const int xcd = wg & 7;
    const int pos = wg >> 3;          // 0..95
    const int j   = pos & 15;         // ntile
    const int r   = (pos >> 4) * 8 + xcd;   // record rank 0..47

    const int* rec = recs + r * RSTRIDE;
    const int cat = rec[0];
    const int nb  = rec[1];
    if (nb == 0) return;
    const int n0 = j * BN;

    __shared__ short xs[2][BM * LDK];   // 80 KB
    __shared__ short wt[2][BN * LDK];   // 10 KB

    const int t    = threadIdx.x;
    const int lane = t & 63;
    const int w    = t >> 6;     // wave 0..15
    const int wm   = w >> 1;     // 0..7
    const int wn   = w & 1;      // 0..1
    const int fl   = lane & 15;
    const int kb   = lane >> 4;

    // X staging: wave w stages batch slot w (rows i*8 + (lane>>3), k (lane&7)*4)
    const int  xrow   = lane >> 3;
    const int  xk4    = (lane & 7) * 4;
    const int  xbatch = rec[2 + w];
    const bool xact   = (w < nb);
    const float* xsrc = x + (size_t)(xbatch * TT + xrow) * DIN + xk4;
    short* xd0 = &xs[0][0] + (w * 32 + xrow) * LDK + xk4;
    short* xd1 = &xs[1][0] + (w * 32 + xrow) * LDK + xk4;

    // W staging: threads 0..127 (waves 0,1); 4x4 register transpose
    const bool wact = (t < 128);
    const int  wk4  = (t & 7) * 4;
    const int  wn4  = ((t >> 3) & 15) * 4;
    const float* wsrc = W + (size_t)cat * (DIN * DH) + (size_t)wk4 * DH + n0 + wn4;

    // MFMA active iff this wave's 64-row band intersects real rows
    const bool mact = (wm * 2 < nb);

    float bv[2];
#pragma unroll
    for (int ni = 0; ni < 2; ++ni)
        bv[ni] = bias[cat * DH + n0 + wn * 32 + ni * 16 + fl];

    f32x4 acc[4][2];
#pragma unroll
    for (int i = 0; i < 4; ++i)
#pragma unroll
        for (int q = 0; q < 2; ++q)
            acc[i][q] = (f32x4){0.f, 0.f, 0.f, 0.f};

    const short* ap0 = &xs[0][0] + (wm * 64 + fl) * LDK + kb * 8;
    const short* ap1 = &xs[1][0] + (wm * 64 + fl) * LDK + kb * 8;
    const short* bp0 = &wt[0][0] + (wn * 32 + fl) * LDK + kb * 8;
    const short* bp1 = &wt[1][0] + (wn * 32 + fl) * LDK + kb * 8;

    // prologue: load K-tile 0
    f32x4 xv[4], wv[4];
    if (xact) {
#pragma unroll
        for (int i = 0; i < 4; ++i)
            xv[i] = *(const f32x4*)(xsrc + (size_t)(i * 8) * DIN);
    }
    if (wact) {
#pragma unroll
        for (int i = 0; i < 4; ++i)
            wv[i] = *(const f32x4*)(wsrc + (size_t)i * DH);
    }

    for (int it = 0; it < NITER; it += 2) {
        gemm_step(xv, wv, xd0, &wt[0][0], ap0, bp0, xsrc, wsrc,
                  xact, wact, mact, wn4, wk4, it, acc);
        gemm_step(xv, wv, xd1, &wt[1][0], ap1, bp1, xsrc, wsrc,
                  xact, wact, mact, wn4, wk4, it + 1, acc);
    }

    // --- epilogue: bias + store rows of real batch slots ---
    if (mact) {
#pragma unroll
        for (int mi = 0; mi < 4; ++mi) {
            const int slot = wm * 2 + (mi >> 1);
            if (slot < nb) {
                const int batch = rec[2 + slot];
                const int rb = (mi & 1) * 16 + kb * 4;
#pragma unroll
                for (int jj = 0; jj < 4; ++jj) {
                    const int trow = rb + jj;
                    float* orow = out + (size_t)(batch * TT + trow) * DH + n0 + wn * 32;
#pragma unroll
                    for (int ni = 0; ni < 2; ++ni)
                        orow[ni * 16 + fl] = acc[mi][ni][jj] + bv[ni];
                }
            }
        }
    }
}

extern "C" void kernel_launch(void* const* d_in, const int* in_sizes, int n_in,
                              void* d_out, int out_size, void* d_ws, size_t ws_size,
                              hipStream_t stream) {
    const float* x       = (const float*)d_in[0];
    const int*   cat_ids = (const int*)d_in[1];
    const float* W       = (const float*)d_in[2];
    const float* bias    = (const float*)d_in[3];
    float*       out     = (float*)d_out;
    int*         recs    = (int*)d_ws;

    hipLaunchKernelGGL(cat_setup_kernel, dim3(1), dim3(256), 0, stream,
                       cat_ids, recs);
    // grid: (NRECPAD/8) * NTILES * 8 = 6*16*8 = 768; inactive records exit fast
    hipLaunchKernelGGL(cat_gemm_kernel, dim3((NRECPAD / 8) * NTILES * 8),
                       dim3(1024), 0, stream, x, W, bias, recs, out);
}